// Round 7
// baseline (456.898 us; speedup 1.0000x reference)
//
#include <hip/hip_runtime.h>

typedef _Float16 h2 __attribute__((ext_vector_type(2)));
typedef _Float16 h4 __attribute__((ext_vector_type(4)));
typedef _Float16 h8 __attribute__((ext_vector_type(8)));
typedef float    f4 __attribute__((ext_vector_type(4)));

#define TT 512
#define NB 512
#define II 32
#define HH 64
#define BT 16          // batch tile per block
#define LROW 72        // padded LDS row (f16 units): 144B -> conflict-free frag reads

static __device__ __forceinline__ float fexp2f(float x){ return __builtin_amdgcn_exp2f(x); }
static __device__ __forceinline__ float frcpf(float x){ return __builtin_amdgcn_rcpf(x); }
static __device__ __forceinline__ float sigf(float x){ return frcpf(1.0f + fexp2f(-1.442695040888963f*x)); }
static __device__ __forceinline__ float tanhf_fast(float x){ return 1.0f - 2.0f*frcpf(1.0f + fexp2f(2.885390081777926f*x)); }

struct H8S { h2 a,b,c,d; };
struct H4S { h2 a,b; };
static __device__ __forceinline__ h2 pkrtz(float a, float b){
  return __builtin_bit_cast(h2, __builtin_amdgcn_cvt_pkrtz(a, b));
}
static __device__ __forceinline__ h8 pack8(h2 a, h2 b, h2 c, h2 d){
  H8S s{a,b,c,d}; return __builtin_bit_cast(h8, s);
}
// load 8 consecutive f32 (16B-aligned) from global, convert to packed h8
static __device__ __forceinline__ h8 ld8cvt(const float* p){
  float4 a = ((const float4*)p)[0], b = ((const float4*)p)[1];
  return pack8(pkrtz(a.x,a.y), pkrtz(a.z,a.w), pkrtz(b.x,b.y), pkrtz(b.z,b.w));
}
static __device__ __forceinline__ f4 mfma16(h8 a, h8 b, f4 c){
  return __builtin_amdgcn_mfma_f32_16x16x32_f16(a, b, c, 0, 0, 0);
}

// Grid 32 blocks x 256 threads; block = 16 batches; wave w owns row-tiles
// {w, w+4, w+8} => all three gates of units [16w,16w+16).
// A-frag layout assumed: A[m][k], m = lane&15, k = 8*(lane>>4)+i (i=0..7).
// B-frag: B[k][n], n = lane&15, k = 8*(lane>>4)+i.
// C/D (verified m89): col n = lane&15, row m = (lane>>4)*4 + reg.
__global__ __launch_bounds__(256, 1)
void gru2_mfma(
    const float* __restrict__ x,
    const float* __restrict__ Wih0, const float* __restrict__ Whh0,
    const float* __restrict__ bih0, const float* __restrict__ bhh0,
    const float* __restrict__ Wih1, const float* __restrict__ Whh1,
    const float* __restrict__ b_ih1, const float* __restrict__ b_hh1,
    const float* __restrict__ fcw, const float* __restrict__ fcb,
    float* __restrict__ out)
{
  const int tid  = threadIdx.x;
  const int w    = tid >> 6;        // wave 0..3
  const int lane = tid & 63;
  const int n    = lane & 15;       // batch within tile / row-within-tile for A
  const int g    = lane >> 4;       // k-group / reg-row group
  const int b0   = blockIdx.x * BT;

  __shared__ _Float16 h0L[2*16*LROW];  // [buf][n][k] f16, padded rows
  __shared__ _Float16 h1L[2*16*LROW];
  __shared__ float    fcred[16*16];

  for (int i = tid; i < 2*16*LROW; i += 256){ h0L[i] = (_Float16)0; h1L[i] = (_Float16)0; }

  // ---------------- persistent A-frags (weights, f16) ----------------
  const int r0 = 16*w + n, r1 = 64 + 16*w + n, r2 = 128 + 16*w + n;
  h8 Arx  = ld8cvt(Wih0 + r0*II + 8*g);   // L0 r-gate, x part (K=32)
  h8 Azx  = ld8cvt(Wih0 + r1*II + 8*g);
  h8 Anix = ld8cvt(Wih0 + r2*II + 8*g);   // L0 n-gate input part
  h8 Arh[2], Azh[2], Anhh[2];             // L0 h part (K=64)
  h8 A1r0[2], A1z0[2], A1ni0[2];          // L1, h0_new part (W_ih1)
  h8 A1r1[2], A1z1[2], A1nh1[2];          // L1, h1 part (W_hh1)
#pragma unroll
  for (int c = 0; c < 2; ++c){
    Arh[c]   = ld8cvt(Whh0 + r0*HH + 32*c + 8*g);
    Azh[c]   = ld8cvt(Whh0 + r1*HH + 32*c + 8*g);
    Anhh[c]  = ld8cvt(Whh0 + r2*HH + 32*c + 8*g);
    A1r0[c]  = ld8cvt(Wih1 + r0*HH + 32*c + 8*g);
    A1z0[c]  = ld8cvt(Wih1 + r1*HH + 32*c + 8*g);
    A1ni0[c] = ld8cvt(Wih1 + r2*HH + 32*c + 8*g);
    A1r1[c]  = ld8cvt(Whh1 + r0*HH + 32*c + 8*g);
    A1z1[c]  = ld8cvt(Whh1 + r1*HH + 32*c + 8*g);
    A1nh1[c] = ld8cvt(Whh1 + r2*HH + 32*c + 8*g);
  }

  // biases for the 4 units this lane owns: j = j0..j0+3
  const int j0 = 16*w + 4*g;
  float br0[4], bz0[4], bin0[4], bhn0[4], br1[4], bz1[4], bin1[4], bhn1[4];
#pragma unroll
  for (int i = 0; i < 4; ++i){
    br0[i]  = bih0[j0+i]      + bhh0[j0+i];
    bz0[i]  = bih0[64+j0+i]   + bhh0[64+j0+i];
    bin0[i] = bih0[128+j0+i];
    bhn0[i] = bhh0[128+j0+i];
    br1[i]  = b_ih1[j0+i]     + b_hh1[j0+i];
    bz1[i]  = b_ih1[64+j0+i]  + b_hh1[64+j0+i];
    bin1[i] = b_ih1[128+j0+i];
    bhn1[i] = b_hh1[128+j0+i];
  }

  float h0p[4] = {0,0,0,0}, h1p[4] = {0,0,0,0};  // recurrent carries (f32, lane-local)

  const float* xrow = x + (size_t)(b0+n)*TT*II + 8*g;
  h8 bx = ld8cvt(xrow);  // x_0 B-frag

  int buf = 0;
  __syncthreads();

  for (int t = 0; t < TT; ++t){
    // ---- B-frags from current buffers ----
    const _Float16* h0r = &h0L[(buf*16 + n)*LROW];
    const _Float16* h1r = &h1L[(buf*16 + n)*LROW];
    h8 bh0a = *(const h8*)(h0r + 8*g);
    h8 bh0b = *(const h8*)(h0r + 32 + 8*g);
    h8 bh1a = *(const h8*)(h1r + 8*g);
    h8 bh1b = *(const h8*)(h1r + 32 + 8*g);

    // ---- L0 MFMAs (x + h0_old) ----
    f4 Cr = {0,0,0,0}, Cz = {0,0,0,0}, Cni = {0,0,0,0}, Cnh = {0,0,0,0};
    Cr  = mfma16(Arx,  bx, Cr);
    Cz  = mfma16(Azx,  bx, Cz);
    Cni = mfma16(Anix, bx, Cni);
    Cr  = mfma16(Arh[0],  bh0a, Cr);   Cr  = mfma16(Arh[1],  bh0b, Cr);
    Cz  = mfma16(Azh[0],  bh0a, Cz);   Cz  = mfma16(Azh[1],  bh0b, Cz);
    Cnh = mfma16(Anhh[0], bh0a, Cnh);  Cnh = mfma16(Anhh[1], bh0b, Cnh);

    // ---- L1 MFMAs that only need h1_old: issue early (overlap L0 gates) ----
    f4 Dr = {0,0,0,0}, Dz = {0,0,0,0}, Dnh = {0,0,0,0};
    Dr  = mfma16(A1r1[0],  bh1a, Dr);   Dr  = mfma16(A1r1[1],  bh1b, Dr);
    Dz  = mfma16(A1z1[0],  bh1a, Dz);   Dz  = mfma16(A1z1[1],  bh1b, Dz);
    Dnh = mfma16(A1nh1[0], bh1a, Dnh);  Dnh = mfma16(A1nh1[1], bh1b, Dnh);

    // prefetch next x frag (latency hidden under gates/MFMA)
    h8 bxn = ld8cvt(xrow + ((t+1 < TT) ? (t+1) : t)*II);

    // ---- L0 gates (lane-local; units j0..j0+3, batch n) ----
    float h0n_[4];
#pragma unroll
    for (int i = 0; i < 4; ++i){
      const float r  = sigf(Cr[i] + br0[i]);
      const float z  = sigf(Cz[i] + bz0[i]);
      const float nn = tanhf_fast(Cni[i] + bin0[i] + r*(Cnh[i] + bhn0[i]));
      h0n_[i] = nn + z*(h0p[i] - nn);
      h0p[i]  = h0n_[i];
    }
    {
      H4S s{ pkrtz(h0n_[0], h0n_[1]), pkrtz(h0n_[2], h0n_[3]) };
      *(h4*)(&h0L[((buf^1)*16 + n)*LROW + j0]) = __builtin_bit_cast(h4, s);
    }
    __syncthreads();   // h0_new visible to all waves

    // ---- L1 MFMAs on h0_new ----
    const _Float16* h0nr = &h0L[((buf^1)*16 + n)*LROW];
    h8 b0a = *(const h8*)(h0nr + 8*g);
    h8 b0b = *(const h8*)(h0nr + 32 + 8*g);
    f4 Dni = {0,0,0,0};
    Dr  = mfma16(A1r0[0],  b0a, Dr);   Dr  = mfma16(A1r0[1],  b0b, Dr);
    Dz  = mfma16(A1z0[0],  b0a, Dz);   Dz  = mfma16(A1z0[1],  b0b, Dz);
    Dni = mfma16(A1ni0[0], b0a, Dni);  Dni = mfma16(A1ni0[1], b0b, Dni);

    // ---- L1 gates ----
    float h1n_[4];
#pragma unroll
    for (int i = 0; i < 4; ++i){
      const float r  = sigf(Dr[i] + br1[i]);
      const float z  = sigf(Dz[i] + bz1[i]);
      const float nn = tanhf_fast(Dni[i] + bin1[i] + r*(Dnh[i] + bhn1[i]));
      h1n_[i] = nn + z*(h1p[i] - nn);
      h1p[i]  = h1n_[i];
    }
    {
      H4S s{ pkrtz(h1n_[0], h1n_[1]), pkrtz(h1n_[2], h1n_[3]) };
      *(h4*)(&h1L[((buf^1)*16 + n)*LROW + j0]) = __builtin_bit_cast(h4, s);
    }
    __syncthreads();   // h1_new visible; also fences buffer reuse

    buf ^= 1;
    bx = bxn;
  }

  // ---------------- FC epilogue: out[b] = fcb + sum_j fcw[j]*h1[j][b] ----------------
  float fw[4];
#pragma unroll
  for (int i = 0; i < 4; ++i) fw[i] = fcw[j0+i];
  float partial = fw[0]*h1p[0] + fw[1]*h1p[1] + fw[2]*h1p[2] + fw[3]*h1p[3];
  fcred[(w*4 + g)*16 + n] = partial;
  __syncthreads();
  if (tid < 16){
    float s = fcb[0];
#pragma unroll
    for (int q = 0; q < 16; ++q) s += fcred[q*16 + tid];
    out[b0 + tid] = s;
  }
}

extern "C" void kernel_launch(void* const* d_in, const int* in_sizes, int n_in,
                              void* d_out, int out_size, void* d_ws, size_t ws_size,
                              hipStream_t stream) {
  const float* x    = (const float*)d_in[0];
  const float* Wih0 = (const float*)d_in[1];
  const float* Whh0 = (const float*)d_in[2];
  const float* bih0 = (const float*)d_in[3];
  const float* bhh0 = (const float*)d_in[4];
  const float* Wih1 = (const float*)d_in[5];
  const float* Whh1 = (const float*)d_in[6];
  const float* bih1 = (const float*)d_in[7];
  const float* bhh1 = (const float*)d_in[8];
  const float* fcw  = (const float*)d_in[9];
  const float* fcb  = (const float*)d_in[10];
  float* out = (float*)d_out;

  gru2_mfma<<<dim3(NB/BT), dim3(256), 0, stream>>>(
      x, Wih0, Whh0, bih0, bhh0, Wih1, Whh1, bih1, bhh1, fcw, fcb, out);
}

// Round 8
// 320.562 us; speedup vs baseline: 1.4253x; 1.4253x over previous
//
#include <hip/hip_runtime.h>

typedef _Float16 h2 __attribute__((ext_vector_type(2)));
typedef _Float16 h4 __attribute__((ext_vector_type(4)));
typedef _Float16 h8 __attribute__((ext_vector_type(8)));
typedef float    f4 __attribute__((ext_vector_type(4)));

#define TT 512
#define NB 512
#define II 32
#define HH 64
#define BT 16          // batch tile per block
#define LROW 72        // padded LDS row (f16 units)

static __device__ __forceinline__ float fexp2f(float x){ return __builtin_amdgcn_exp2f(x); }
static __device__ __forceinline__ float frcpf(float x){ return __builtin_amdgcn_rcpf(x); }
static __device__ __forceinline__ float sigf(float x){ return frcpf(1.0f + fexp2f(-1.442695040888963f*x)); }
static __device__ __forceinline__ float tanhf_fast(float x){ return 1.0f - 2.0f*frcpf(1.0f + fexp2f(2.885390081777926f*x)); }

struct H8S { h2 a,b,c,d; };
struct H4S { h2 a,b; };
static __device__ __forceinline__ h2 pkrtz(float a, float b){
  return __builtin_bit_cast(h2, __builtin_amdgcn_cvt_pkrtz(a, b));
}
static __device__ __forceinline__ h8 pack8(h2 a, h2 b, h2 c, h2 d){
  H8S s{a,b,c,d}; return __builtin_bit_cast(h8, s);
}
static __device__ __forceinline__ h8 ld8cvt(const float* p){
  float4 a = ((const float4*)p)[0], b = ((const float4*)p)[1];
  return pack8(pkrtz(a.x,a.y), pkrtz(a.z,a.w), pkrtz(b.x,b.y), pkrtz(b.z,b.w));
}
static __device__ __forceinline__ f4 mfma16(h8 a, h8 b, f4 c){
  return __builtin_amdgcn_mfma_f32_16x16x32_f16(a, b, c, 0, 0, 0);
}

// 32 blocks x 512 threads (8 waves). Waves 0-3: layer0; waves 4-7: layer1,
// software-pipelined one step behind. Phase p: L0 computes h0[p] from
// h0[p-1],x[p]; L1 computes h1[p-1] from h0[p-1],h1[p-2]. ONE barrier/phase,
// layer chains in parallel (R7 had 2 barriers + sequential layers/step).
// Fragment layouts identical to R7 (verified: absmax 9.8e-4).
__global__ __attribute__((amdgpu_flat_work_group_size(512,512)))
void gru2_pipe(
    const float* __restrict__ x,
    const float* __restrict__ Wih0, const float* __restrict__ Whh0,
    const float* __restrict__ bih0, const float* __restrict__ bhh0,
    const float* __restrict__ Wih1, const float* __restrict__ Whh1,
    const float* __restrict__ b_ih1, const float* __restrict__ b_hh1,
    const float* __restrict__ fcw, const float* __restrict__ fcb,
    float* __restrict__ out)
{
  const int tid  = threadIdx.x;
  const int w    = tid >> 6;        // wave 0..7
  const int lane = tid & 63;
  const int c    = lane & 15;       // batch within tile
  const int g    = lane >> 4;       // k-group / reg-row group
  const int wt   = w & 3;           // row-tile index within layer group
  const bool isL0 = (w < 4);
  const int b0   = blockIdx.x * BT;

  __shared__ _Float16 h0L[2][16*LROW];
  __shared__ _Float16 h1L[2][16*LROW];
  __shared__ float    fcred[256];

  for (int i = tid; i < 16*LROW; i += 512){
    h0L[0][i] = (_Float16)0; h0L[1][i] = (_Float16)0;
    h1L[0][i] = (_Float16)0; h1L[1][i] = (_Float16)0;
  }

  // ---- persistent A-frags: each wave loads only its layer's weights ----
  const int r0 = 16*wt + c, r1 = 64 + 16*wt + c, r2 = 128 + 16*wt + c;
  const int j0 = 16*wt + 4*g;          // units this lane owns

  h8 Ax[3];        // L0: x-part rows (r,z,ni), K=32
  h8 Ah[3][2];     // L0: h-part rows (r,z,nh), K=64
  h8 P0[3][2];     // L1: h0-part (Wih1) rows (r,z,ni)
  h8 P1[3][2];     // L1: h1-part (Whh1) rows (r,z,nh)
  float gbr[4], gbz[4], gbi[4], gbh[4];

  if (isL0) {
    Ax[0] = ld8cvt(Wih0 + r0*II + 8*g);
    Ax[1] = ld8cvt(Wih0 + r1*II + 8*g);
    Ax[2] = ld8cvt(Wih0 + r2*II + 8*g);
#pragma unroll
    for (int q = 0; q < 2; ++q){
      Ah[0][q] = ld8cvt(Whh0 + r0*HH + 32*q + 8*g);
      Ah[1][q] = ld8cvt(Whh0 + r1*HH + 32*q + 8*g);
      Ah[2][q] = ld8cvt(Whh0 + r2*HH + 32*q + 8*g);
    }
#pragma unroll
    for (int i = 0; i < 4; ++i){
      gbr[i] = bih0[j0+i]     + bhh0[j0+i];
      gbz[i] = bih0[64+j0+i]  + bhh0[64+j0+i];
      gbi[i] = bih0[128+j0+i];
      gbh[i] = bhh0[128+j0+i];
    }
  } else {
#pragma unroll
    for (int q = 0; q < 2; ++q){
      P0[0][q] = ld8cvt(Wih1 + r0*HH + 32*q + 8*g);
      P0[1][q] = ld8cvt(Wih1 + r1*HH + 32*q + 8*g);
      P0[2][q] = ld8cvt(Wih1 + r2*HH + 32*q + 8*g);
      P1[0][q] = ld8cvt(Whh1 + r0*HH + 32*q + 8*g);
      P1[1][q] = ld8cvt(Whh1 + r1*HH + 32*q + 8*g);
      P1[2][q] = ld8cvt(Whh1 + r2*HH + 32*q + 8*g);
    }
#pragma unroll
    for (int i = 0; i < 4; ++i){
      gbr[i] = b_ih1[j0+i]     + b_hh1[j0+i];
      gbz[i] = b_ih1[64+j0+i]  + b_hh1[64+j0+i];
      gbi[i] = b_ih1[128+j0+i];
      gbh[i] = b_hh1[128+j0+i];
    }
  }

  float hp[4] = {0.f,0.f,0.f,0.f};   // recurrent carry (L0: h0; L1: h1)

  const float* xrow = x + (size_t)(b0+c)*TT*II + 8*g;
  h8 bx = ld8cvt(xrow);              // x[0] B-frag (only L0 uses)

  int buf = 0;
  __syncthreads();

  for (int p = 0; p <= TT; ++p){
    if (isL0) {
      if (p < TT) {
        const _Float16* h0r = &h0L[buf][c*LROW];
        h8 ba = *(const h8*)(h0r + 8*g);
        h8 bb = *(const h8*)(h0r + 32 + 8*g);
        f4 Cr = {0,0,0,0}, Cz = {0,0,0,0}, Cni = {0,0,0,0}, Cnh = {0,0,0,0};
        Cr  = mfma16(Ax[0], bx, Cr);
        Cz  = mfma16(Ax[1], bx, Cz);
        Cni = mfma16(Ax[2], bx, Cni);
        Cr  = mfma16(Ah[0][0], ba, Cr);   Cr  = mfma16(Ah[0][1], bb, Cr);
        Cz  = mfma16(Ah[1][0], ba, Cz);   Cz  = mfma16(Ah[1][1], bb, Cz);
        Cnh = mfma16(Ah[2][0], ba, Cnh);  Cnh = mfma16(Ah[2][1], bb, Cnh);
        // prefetch next x frag while MFMAs/gates run
        h8 bxn = ld8cvt(xrow + ((p+1 < TT) ? (p+1) : (TT-1))*II);
#pragma unroll
        for (int i = 0; i < 4; ++i){
          const float r  = sigf(Cr[i] + gbr[i]);
          const float z  = sigf(Cz[i] + gbz[i]);
          const float nn = tanhf_fast(Cni[i] + gbi[i] + r*(Cnh[i] + gbh[i]));
          hp[i] = nn + z*(hp[i] - nn);
        }
        H4S s{ pkrtz(hp[0], hp[1]), pkrtz(hp[2], hp[3]) };
        *(h4*)(&h0L[buf^1][c*LROW + j0]) = __builtin_bit_cast(h4, s);
        bx = bxn;
      }
    } else {
      if (p >= 1) {
        const _Float16* h0r = &h0L[buf][c*LROW];   // h0[p-1]
        const _Float16* h1r = &h1L[buf][c*LROW];   // h1[p-2]
        h8 a0 = *(const h8*)(h0r + 8*g);
        h8 a1 = *(const h8*)(h0r + 32 + 8*g);
        h8 v0 = *(const h8*)(h1r + 8*g);
        h8 v1 = *(const h8*)(h1r + 32 + 8*g);
        f4 Dr = {0,0,0,0}, Dz = {0,0,0,0}, Dni = {0,0,0,0}, Dnh = {0,0,0,0};
        Dr  = mfma16(P0[0][0], a0, Dr);   Dr  = mfma16(P0[0][1], a1, Dr);
        Dr  = mfma16(P1[0][0], v0, Dr);   Dr  = mfma16(P1[0][1], v1, Dr);
        Dz  = mfma16(P0[1][0], a0, Dz);   Dz  = mfma16(P0[1][1], a1, Dz);
        Dz  = mfma16(P1[1][0], v0, Dz);   Dz  = mfma16(P1[1][1], v1, Dz);
        Dni = mfma16(P0[2][0], a0, Dni);  Dni = mfma16(P0[2][1], a1, Dni);
        Dnh = mfma16(P1[2][0], v0, Dnh);  Dnh = mfma16(P1[2][1], v1, Dnh);
#pragma unroll
        for (int i = 0; i < 4; ++i){
          const float r  = sigf(Dr[i] + gbr[i]);
          const float z  = sigf(Dz[i] + gbz[i]);
          const float nn = tanhf_fast(Dni[i] + gbi[i] + r*(Dnh[i] + gbh[i]));
          hp[i] = nn + z*(hp[i] - nn);
        }
        H4S s{ pkrtz(hp[0], hp[1]), pkrtz(hp[2], hp[3]) };
        *(h4*)(&h1L[buf^1][c*LROW + j0]) = __builtin_bit_cast(h4, s);
      }
    }
    __syncthreads();
    buf ^= 1;
  }

  // ---- FC epilogue: L1 waves hold h1[TT-1] in hp ----
  if (!isL0) {
    float s = fcw[j0]*hp[0] + fcw[j0+1]*hp[1] + fcw[j0+2]*hp[2] + fcw[j0+3]*hp[3];
    fcred[(wt*4 + g)*16 + c] = s;
  }
  __syncthreads();
  if (tid < 16){
    float s = fcb[0];
#pragma unroll
    for (int q = 0; q < 16; ++q) s += fcred[q*16 + tid];
    out[b0 + tid] = s;
  }
}

extern "C" void kernel_launch(void* const* d_in, const int* in_sizes, int n_in,
                              void* d_out, int out_size, void* d_ws, size_t ws_size,
                              hipStream_t stream) {
  const float* x    = (const float*)d_in[0];
  const float* Wih0 = (const float*)d_in[1];
  const float* Whh0 = (const float*)d_in[2];
  const float* bih0 = (const float*)d_in[3];
  const float* bhh0 = (const float*)d_in[4];
  const float* Wih1 = (const float*)d_in[5];
  const float* Whh1 = (const float*)d_in[6];
  const float* bih1 = (const float*)d_in[7];
  const float* bhh1 = (const float*)d_in[8];
  const float* fcw  = (const float*)d_in[9];
  const float* fcb  = (const float*)d_in[10];
  float* out = (float*)d_out;

  gru2_pipe<<<dim3(NB/BT), dim3(512), 0, stream>>>(
      x, Wih0, Whh0, bih0, bhh0, Wih1, Whh1, bih1, bhh1, fcw, fcb, out);
}

// Round 9
// 304.734 us; speedup vs baseline: 1.4993x; 1.0519x over previous
//
#include <hip/hip_runtime.h>

typedef _Float16 h2 __attribute__((ext_vector_type(2)));
typedef _Float16 h4 __attribute__((ext_vector_type(4)));
typedef _Float16 h8 __attribute__((ext_vector_type(8)));
typedef float    f4 __attribute__((ext_vector_type(4)));

#define TT 512
#define NB 512
#define II 32
#define HH 64
#define BT 16          // batch tile per block
#define LROW 72        // padded LDS row (f16 units)

static __device__ __forceinline__ float fexp2f(float x){ return __builtin_amdgcn_exp2f(x); }
static __device__ __forceinline__ float frcpf(float x){ return __builtin_amdgcn_rcpf(x); }
static __device__ __forceinline__ float sigf(float x){ return frcpf(1.0f + fexp2f(-1.442695040888963f*x)); }
static __device__ __forceinline__ float tanhf_fast(float x){ return 1.0f - 2.0f*frcpf(1.0f + fexp2f(2.885390081777926f*x)); }

struct H8S { h2 a,b,c,d; };
struct H4S { h2 a,b; };
static __device__ __forceinline__ h2 pkrtz(float a, float b){
  return __builtin_bit_cast(h2, __builtin_amdgcn_cvt_pkrtz(a, b));
}
static __device__ __forceinline__ h8 pack8(h2 a, h2 b, h2 c, h2 d){
  H8S s{a,b,c,d}; return __builtin_bit_cast(h8, s);
}
static __device__ __forceinline__ h8 cvt8(float4 a, float4 b){
  return pack8(pkrtz(a.x,a.y), pkrtz(a.z,a.w), pkrtz(b.x,b.y), pkrtz(b.z,b.w));
}
static __device__ __forceinline__ h8 ld8cvt(const float* p){
  return cvt8(((const float4*)p)[0], ((const float4*)p)[1]);
}
static __device__ __forceinline__ f4 mfma16(h8 a, h8 b, f4 c){
  return __builtin_amdgcn_mfma_f32_16x16x32_f16(a, b, c, 0, 0, 0);
}

// 32 blocks x 512 threads (8 waves). Waves 0-3: layer0; waves 4-7: layer1,
// software-pipelined one step behind (one barrier/phase). R9: depth-2 x
// prefetch held in RAW float4 regs (convert at use -> the vmcnt wait for
// x[p+2] can't serialize phase p; R8's depth-1 convert-at-load stalled
// ~1000cy/phase on HBM latency). Bias pre-loaded into MFMA C-operand.
__global__ __attribute__((amdgpu_flat_work_group_size(512,512)))
void gru2_pipe(
    const float* __restrict__ x,
    const float* __restrict__ Wih0, const float* __restrict__ Whh0,
    const float* __restrict__ bih0, const float* __restrict__ bhh0,
    const float* __restrict__ Wih1, const float* __restrict__ Whh1,
    const float* __restrict__ b_ih1, const float* __restrict__ b_hh1,
    const float* __restrict__ fcw, const float* __restrict__ fcb,
    float* __restrict__ out)
{
  const int tid  = threadIdx.x;
  const int w    = tid >> 6;        // wave 0..7
  const int lane = tid & 63;
  const int c    = lane & 15;       // batch within tile
  const int g    = lane >> 4;       // k-group / reg-row group
  const int wt   = w & 3;           // row-tile index within layer group
  const bool isL0 = (w < 4);
  const int b0   = blockIdx.x * BT;

  __shared__ _Float16 h0L[2][16*LROW];
  __shared__ _Float16 h1L[2][16*LROW];
  __shared__ float    fcred[256];

  for (int i = tid; i < 16*LROW; i += 512){
    h0L[0][i] = (_Float16)0; h0L[1][i] = (_Float16)0;
    h1L[0][i] = (_Float16)0; h1L[1][i] = (_Float16)0;
  }

  // ---- persistent A-frags: each wave loads only its layer's weights ----
  const int r0 = 16*wt + c, r1 = 64 + 16*wt + c, r2 = 128 + 16*wt + c;
  const int j0 = 16*wt + 4*g;          // units this lane owns

  h8 Ax[3];        // L0: x-part rows (r,z,ni), K=32
  h8 Ah[3][2];     // L0: h-part rows (r,z,nh), K=64
  h8 P0[3][2];     // L1: h0-part (Wih1) rows (r,z,ni)
  h8 P1[3][2];     // L1: h1-part (Whh1) rows (r,z,nh)
  f4 brv, bzv, biv, bhv;               // per-lane bias vectors (C-init)

  if (isL0) {
    Ax[0] = ld8cvt(Wih0 + r0*II + 8*g);
    Ax[1] = ld8cvt(Wih0 + r1*II + 8*g);
    Ax[2] = ld8cvt(Wih0 + r2*II + 8*g);
#pragma unroll
    for (int q = 0; q < 2; ++q){
      Ah[0][q] = ld8cvt(Whh0 + r0*HH + 32*q + 8*g);
      Ah[1][q] = ld8cvt(Whh0 + r1*HH + 32*q + 8*g);
      Ah[2][q] = ld8cvt(Whh0 + r2*HH + 32*q + 8*g);
    }
#pragma unroll
    for (int i = 0; i < 4; ++i){
      brv[i] = bih0[j0+i]     + bhh0[j0+i];
      bzv[i] = bih0[64+j0+i]  + bhh0[64+j0+i];
      biv[i] = bih0[128+j0+i];
      bhv[i] = bhh0[128+j0+i];
    }
  } else {
#pragma unroll
    for (int q = 0; q < 2; ++q){
      P0[0][q] = ld8cvt(Wih1 + r0*HH + 32*q + 8*g);
      P0[1][q] = ld8cvt(Wih1 + r1*HH + 32*q + 8*g);
      P0[2][q] = ld8cvt(Wih1 + r2*HH + 32*q + 8*g);
      P1[0][q] = ld8cvt(Whh1 + r0*HH + 32*q + 8*g);
      P1[1][q] = ld8cvt(Whh1 + r1*HH + 32*q + 8*g);
      P1[2][q] = ld8cvt(Whh1 + r2*HH + 32*q + 8*g);
    }
#pragma unroll
    for (int i = 0; i < 4; ++i){
      brv[i] = b_ih1[j0+i]     + b_hh1[j0+i];
      bzv[i] = b_ih1[64+j0+i]  + b_hh1[64+j0+i];
      biv[i] = b_ih1[128+j0+i];
      bhv[i] = b_hh1[128+j0+i];
    }
  }

  float hp[4] = {0.f,0.f,0.f,0.f};   // recurrent carry (L0: h0; L1: h1)

  // depth-2 x prefetch, RAW f32 (convert only at use)
  const float* xrow = x + (size_t)(b0+c)*TT*II + 8*g;
  float4 x0a, x0b, x1a, x1b;
  if (isL0) {
    x0a = ((const float4*)xrow)[0];       x0b = ((const float4*)xrow)[1];
    x1a = ((const float4*)(xrow+II))[0];  x1b = ((const float4*)(xrow+II))[1];
  }

  int buf = 0;
  __syncthreads();

  for (int p = 0; p <= TT; ++p){
    if (isL0) {
      if (p < TT) {
        const _Float16* h0r = &h0L[buf][c*LROW];
        h8 ba = *(const h8*)(h0r + 8*g);
        h8 bb = *(const h8*)(h0r + 32 + 8*g);
        h8 bx = cvt8(x0a, x0b);            // convert x[p] now (load landed >=2 phases ago)
        f4 Cr = brv, Cz = bzv, Cni = biv, Cnh = bhv;
        Cr  = mfma16(Ax[0], bx, Cr);
        Cz  = mfma16(Ax[1], bx, Cz);
        Cni = mfma16(Ax[2], bx, Cni);
        Cr  = mfma16(Ah[0][0], ba, Cr);   Cr  = mfma16(Ah[0][1], bb, Cr);
        Cz  = mfma16(Ah[1][0], ba, Cz);   Cz  = mfma16(Ah[1][1], bb, Cz);
        Cnh = mfma16(Ah[2][0], ba, Cnh);  Cnh = mfma16(Ah[2][1], bb, Cnh);
        // shift prefetch window; issue load for x[p+2] (2 phases to land)
        x0a = x1a; x0b = x1b;
        {
          const float* pn = xrow + (size_t)((p+2 < TT) ? (p+2) : (TT-1))*II;
          x1a = ((const float4*)pn)[0];  x1b = ((const float4*)pn)[1];
        }
#pragma unroll
        for (int i = 0; i < 4; ++i){
          const float r  = sigf(Cr[i]);
          const float z  = sigf(Cz[i]);
          const float nn = tanhf_fast(Cni[i] + r*Cnh[i]);
          hp[i] = nn + z*(hp[i] - nn);
        }
        H4S s{ pkrtz(hp[0], hp[1]), pkrtz(hp[2], hp[3]) };
        *(h4*)(&h0L[buf^1][c*LROW + j0]) = __builtin_bit_cast(h4, s);
      }
    } else {
      if (p >= 1) {
        const _Float16* h0r = &h0L[buf][c*LROW];   // h0[p-1]
        const _Float16* h1r = &h1L[buf][c*LROW];   // h1[p-2]
        h8 a0 = *(const h8*)(h0r + 8*g);
        h8 a1 = *(const h8*)(h0r + 32 + 8*g);
        h8 v0 = *(const h8*)(h1r + 8*g);
        h8 v1 = *(const h8*)(h1r + 32 + 8*g);
        f4 Dr = brv, Dz = bzv, Dni = biv, Dnh = bhv;
        Dr  = mfma16(P0[0][0], a0, Dr);   Dr  = mfma16(P0[0][1], a1, Dr);
        Dr  = mfma16(P1[0][0], v0, Dr);   Dr  = mfma16(P1[0][1], v1, Dr);
        Dz  = mfma16(P0[1][0], a0, Dz);   Dz  = mfma16(P0[1][1], a1, Dz);
        Dz  = mfma16(P1[1][0], v0, Dz);   Dz  = mfma16(P1[1][1], v1, Dz);
        Dni = mfma16(P0[2][0], a0, Dni);  Dni = mfma16(P0[2][1], a1, Dni);
        Dnh = mfma16(P1[2][0], v0, Dnh);  Dnh = mfma16(P1[2][1], v1, Dnh);
#pragma unroll
        for (int i = 0; i < 4; ++i){
          const float r  = sigf(Dr[i]);
          const float z  = sigf(Dz[i]);
          const float nn = tanhf_fast(Dni[i] + r*Dnh[i]);
          hp[i] = nn + z*(hp[i] - nn);
        }
        H4S s{ pkrtz(hp[0], hp[1]), pkrtz(hp[2], hp[3]) };
        *(h4*)(&h1L[buf^1][c*LROW + j0]) = __builtin_bit_cast(h4, s);
      }
    }
    __syncthreads();
    buf ^= 1;
  }

  // ---- FC epilogue: L1 waves hold h1[TT-1] in hp ----
  if (!isL0) {
    float s = fcw[j0]*hp[0] + fcw[j0+1]*hp[1] + fcw[j0+2]*hp[2] + fcw[j0+3]*hp[3];
    fcred[(wt*4 + g)*16 + c] = s;
  }
  __syncthreads();
  if (tid < 16){
    float s = fcb[0];
#pragma unroll
    for (int q = 0; q < 16; ++q) s += fcred[q*16 + tid];
    out[b0 + tid] = s;
  }
}

extern "C" void kernel_launch(void* const* d_in, const int* in_sizes, int n_in,
                              void* d_out, int out_size, void* d_ws, size_t ws_size,
                              hipStream_t stream) {
  const float* x    = (const float*)d_in[0];
  const float* Wih0 = (const float*)d_in[1];
  const float* Whh0 = (const float*)d_in[2];
  const float* bih0 = (const float*)d_in[3];
  const float* bhh0 = (const float*)d_in[4];
  const float* Wih1 = (const float*)d_in[5];
  const float* Whh1 = (const float*)d_in[6];
  const float* bih1 = (const float*)d_in[7];
  const float* bhh1 = (const float*)d_in[8];
  const float* fcw  = (const float*)d_in[9];
  const float* fcb  = (const float*)d_in[10];
  float* out = (float*)d_out;

  gru2_pipe<<<dim3(NB/BT), dim3(512), 0, stream>>>(
      x, Wih0, Whh0, bih0, bhh0, Wih1, Whh1, bih1, bhh1, fcw, fcb, out);
}